// Round 7
// baseline (49.570 us; speedup 1.0000x reference)
//
#include <hip/hip_runtime.h>

// DirectionalScan: B=4, H=64, W=64, D=512, N=8
// out = ((scan_h(x) + scan_v(x)) @ Wp^T) + b_proj
//     = [yh | yv] (16384x1024) @ [Wp ; Wp]^T (512x1024) + b   -- K-concat trick
#define BB 4
#define HH 64
#define WW 64
#define DD 512
#define NS 8
#define MROWS (BB * HH * WW)  // 16384

typedef __attribute__((ext_vector_type(8))) __bf16 bf16x8;
typedef __attribute__((ext_vector_type(4))) float f32x4;

__device__ inline short f2bf(float f) {  // RNE f32 -> bf16 bits
  unsigned u = __float_as_uint(f);
  return (short)((u + 0x7fff + ((u >> 16) & 1)) >> 16);
}

// one SSM step: update states s[], return C.s + D*x via 3-level tree
__device__ inline float ssm_step(float xv, float* s, const float* a,
                                 const float* bm, const float* cm, float dk) {
#pragma unroll
  for (int n = 0; n < NS; ++n) s[n] = fmaf(a[n], s[n], bm[n] * xv);
  float p0 = s[0] * cm[0], p1 = s[1] * cm[1], p2 = s[2] * cm[2],
        p3 = s[3] * cm[3], p4 = s[4] * cm[4], p5 = s[5] * cm[5],
        p6 = s[6] * cm[6], p7 = s[7] * cm[7];
  float q0 = p0 + p1, q1 = p2 + p3, q2 = p4 + p5, q3 = p6 + p7;
  return fmaf(dk, xv, (q0 + q1) + (q2 + q3));
}

// ---------------- kernel 1: BOTH scans (independent) + Wp->bf16 -------------
// bx <  512 : h-scan, seq=(b,w), scan over h (stride W*D), writes yh (strided)
// bx < 1024 : v-scan, seq=(b,h), scan over w (stride D), writes yv (coalesced)
// bx >=1024 : 128 blocks convert Wp f32 -> bf16
__global__ __launch_bounds__(256) void scan_both_kernel(
    const float* __restrict__ x, const float* __restrict__ A,
    const float* __restrict__ Bm, const float* __restrict__ Cm,
    const float* __restrict__ Dsk, short* __restrict__ yh,
    short* __restrict__ yv, const float* __restrict__ Wp,
    short* __restrict__ wb) {
  const int bx = (int)blockIdx.x;
  if (bx >= 1024) {
    const int i = ((bx - 1024) * 256 + (int)threadIdx.x) * 8;
    const float4 v0 = *(const float4*)&Wp[i];
    const float4 v1 = *(const float4*)&Wp[i + 4];
    short r[8];
    r[0] = f2bf(v0.x); r[1] = f2bf(v0.y); r[2] = f2bf(v0.z); r[3] = f2bf(v0.w);
    r[4] = f2bf(v1.x); r[5] = f2bf(v1.y); r[6] = f2bf(v1.z); r[7] = f2bf(v1.w);
    *(short4*)&wb[i] = *(short4*)&r[0];
    *(short4*)&wb[i + 4] = *(short4*)&r[4];
    return;
  }

  const bool horiz = (bx < 512);
  const int lx = horiz ? bx : bx - 512;
  const int seq = lx >> 1;                        // 0..255
  const int d = (lx & 1) * 256 + (int)threadIdx.x;
  const int b = seq >> 6;
  const int r = seq & 63;

  size_t base, step;
  short* y;
  if (horiz) {  // r = w, scan over h
    base = ((size_t)b * HH * WW + r) * DD + d;
    step = (size_t)WW * DD;
    y = yh;
  } else {      // r = h, scan over w
    base = ((size_t)(b * HH + r)) * WW * DD + d;
    step = DD;
    y = yv;
  }

  float a[NS], bm[NS], cm[NS], s[NS];
#pragma unroll
  for (int i = 0; i < NS; i += 4) {
    float4 t;
    t = *(const float4*)&A[(size_t)d * NS + i];
    a[i] = t.x; a[i + 1] = t.y; a[i + 2] = t.z; a[i + 3] = t.w;
    t = *(const float4*)&Bm[(size_t)d * NS + i];
    bm[i] = t.x; bm[i + 1] = t.y; bm[i + 2] = t.z; bm[i + 3] = t.w;
    t = *(const float4*)&Cm[(size_t)d * NS + i];
    cm[i] = t.x; cm[i + 1] = t.y; cm[i + 2] = t.z; cm[i + 3] = t.w;
  }
  const float dk = Dsk[d];
#pragma unroll
  for (int i = 0; i < NS; ++i) s[i] = 0.f;

  // 2-chunk-ahead prefetch (4-slot ring; unroll 4 keeps indices static)
  float xs[4][8];
#pragma unroll
  for (int i = 0; i < 8; ++i) xs[0][i] = x[base + (size_t)i * step];
#pragma unroll
  for (int i = 0; i < 8; ++i) xs[1][i] = x[base + (size_t)(8 + i) * step];

#pragma unroll 4
  for (int c = 0; c < 8; ++c) {
    const int cur = c & 3;
    if (c < 6) {
      const size_t pbase = base + 16 * step;
#pragma unroll
      for (int i = 0; i < 8; ++i)
        xs[(c + 2) & 3][i] = x[pbase + (size_t)i * step];
    }
#pragma unroll
    for (int i = 0; i < 8; ++i)
      y[base + (size_t)i * step] = f2bf(ssm_step(xs[cur][i], s, a, bm, cm, dk));
    base += 8 * step;
  }
}

// ---------------- kernel 2: bf16 MFMA GEMM, K'=1024 concat ------------------
// out[m][n] = sum_{k<512} yh[m][k]*W[n][k] + sum_{k<512} yv[m][k]*W[n][k] + b
// m97 structure: 128x128 tile, BK=64, 4 waves (2x2), global_load_lds w16.
#define GBK 64

__global__ __launch_bounds__(256) void gemm_cat(
    const short* __restrict__ Yh, const short* __restrict__ Yv,
    const short* __restrict__ Wb, const float* __restrict__ bias,
    float* __restrict__ out) {
  __shared__ __align__(16) short As[128 * GBK];  // 16 KB, row-major [128][64]
  __shared__ __align__(16) short Bs[128 * GBK];

  // XCD-aware bijective swizzle of a 1-D grid of 512 (64 per XCD chunk)
  const int swz = ((int)blockIdx.x & 7) * 64 + ((int)blockIdx.x >> 3);
  const int n0 = (swz & 3) * 128;   // N=512 -> 4 col-blocks
  const int m0 = (swz >> 2) * 128;  // 128 row-blocks

  const int tid = (int)threadIdx.x;
  const int lane = tid & 63;
  const int wid = tid >> 6;  // 0..3
  const int wm = wid >> 1, wn = wid & 1;

  const int srow = lane >> 3;       // 0..7 row within 8-row chunk
  const int scol = (lane & 7) * 8;  // elem col within row

  f32x4 acc[4][4];
#pragma unroll
  for (int m = 0; m < 4; ++m)
#pragma unroll
    for (int n = 0; n < 4; ++n) acc[m][n] = (f32x4){0.f, 0.f, 0.f, 0.f};

  auto stage = [&](int k0) {
    const short* Asrc = (k0 < DD) ? Yh : Yv;  // K-concat: uniform per step
    const int ka = k0 & (DD - 1);
    const int kb = k0 & (DD - 1);             // B' row repeats Wb along K
#pragma unroll
    for (int c = 0; c < 4; ++c) {
      const int chunk = wid * 4 + c;  // 0..15 (8 rows each)
      const int row = chunk * 8 + srow;
      const short* ga = &Asrc[(size_t)(m0 + row) * DD + ka + scol];
      const short* gb = &Wb[(size_t)(n0 + row) * DD + kb + scol];
      __builtin_amdgcn_global_load_lds(
          (const __attribute__((address_space(1))) unsigned int*)ga,
          (__attribute__((address_space(3))) unsigned int*)((char*)As +
                                                            chunk * 1024),
          16, 0, 0);
      __builtin_amdgcn_global_load_lds(
          (const __attribute__((address_space(1))) unsigned int*)gb,
          (__attribute__((address_space(3))) unsigned int*)((char*)Bs +
                                                            chunk * 1024),
          16, 0, 0);
    }
  };

  const int arow = wm * 64 + (lane & 15);
  const int brow = wn * 64 + (lane & 15);
  const int kfr = (lane >> 4) * 8;

  stage(0);
  const int NK = 2 * DD / GBK;  // 16 K-steps over the 1024 concat-K
  for (int k = 0; k < NK; ++k) {
    __syncthreads();  // staging drained (vmcnt0 before barrier), compute done
#pragma unroll
    for (int kk = 0; kk < GBK; kk += 32) {
      bf16x8 af[4], bfv[4];
      const int kcol = kk + kfr;
#pragma unroll
      for (int m = 0; m < 4; ++m)
        af[m] = *(const bf16x8*)(const void*)&As[(arow + m * 16) * GBK + kcol];
#pragma unroll
      for (int n = 0; n < 4; ++n)
        bfv[n] = *(const bf16x8*)(const void*)&Bs[(brow + n * 16) * GBK + kcol];
#pragma unroll
      for (int m = 0; m < 4; ++m)
#pragma unroll
        for (int n = 0; n < 4; ++n)
          acc[m][n] = __builtin_amdgcn_mfma_f32_16x16x32_bf16(
              af[m], bfv[n], acc[m][n], 0, 0, 0);
    }
    if (k + 1 < NK) {
      __syncthreads();  // all waves done reading LDS
      stage((k + 1) * GBK);
    }
  }

  // epilogue: D layout col=lane&15, row=(lane>>4)*4+j  [m89 verified]
  const int c16 = lane & 15;
  const int r4 = (lane >> 4) * 4;
#pragma unroll
  for (int m = 0; m < 4; ++m) {
    const int rowb = m0 + wm * 64 + m * 16 + r4;
#pragma unroll
    for (int n = 0; n < 4; ++n) {
      const int col = n0 + wn * 64 + n * 16 + c16;
      const float bv = bias[col];
#pragma unroll
      for (int j = 0; j < 4; ++j)
        out[(size_t)(rowb + j) * DD + col] = acc[m][n][j] + bv;
    }
  }
}

// ---------------- launcher ----------------
extern "C" void kernel_launch(void* const* d_in, const int* in_sizes, int n_in,
                              void* d_out, int out_size, void* d_ws,
                              size_t ws_size, hipStream_t stream) {
  const float* x = (const float*)d_in[0];
  const float* A = (const float*)d_in[3];
  const float* Bm = (const float*)d_in[4];
  const float* Cm = (const float*)d_in[5];
  const float* Dsk = (const float*)d_in[6];
  const float* Wp = (const float*)d_in[7];
  const float* bpj = (const float*)d_in[8];
  float* out = (float*)d_out;

  short* yh = (short*)d_ws;                                  // 16 MB bf16
  short* yv = yh + (size_t)MROWS * DD;                       // 16 MB bf16
  short* wb = yv + (size_t)MROWS * DD;                       // 512 KB bf16

  // both scans + Wp conversion, fully parallel (1152 blocks)
  scan_both_kernel<<<1152, 256, 0, stream>>>(x, A, Bm, Cm, Dsk, yh, yv, Wp, wb);

  // K-concat GEMM: 512 blocks (4 n-blocks x 128 m-blocks, XCD-swizzled)
  gemm_cat<<<512, 256, 0, stream>>>(yh, yv, wb, bpj, out);
}